// Round 4
// baseline (45.429 us; speedup 1.0000x reference)
//
#include <hip/hip_runtime.h>

// Separable QP projection via QUADRISECTION on lambda.
// One 256-thread block per row (B=4096, N=4096).
// Each thread owns 16 elements of the row in registers (z, 1/(2*gamma), m, M).
//
// Latency analysis (R3): per-iteration serial chain {eval -> DPP reduce ->
// readlane -> LDS -> barrier -> LDS -> branch} dominates; eval is cheap.
// So: evaluate g at 3 probe points per iteration (independent chains, good
// ILP) -> interval shrinks 4x/iter -> 6 iters == 12 bisections of shrink,
// but HALF the serial reduce/barrier segments.
//
// QITERS=6: width 18/4^6 = 4.4e-3 -> lam err <= 2.2e-3 -> x err ~1.1e-3,
// plus ~4e-3 fp32-sum branch-flip noise floor (measured) << 2e-2 threshold.

#define QITERS 6

// ---- DPP wave64 reduction helpers (gfx9-family row ops) ----
template<int CTRL, int RM>
__device__ __forceinline__ float dpp_add(float v) {
    int t = __builtin_amdgcn_update_dpp(0, __float_as_int(v), CTRL, RM, 0xf, false);
    return v + __int_as_float(t);
}
template<int CTRL, int RM>
__device__ __forceinline__ float dpp_min(float v) {
    int t = __builtin_amdgcn_update_dpp(0x7f800000, __float_as_int(v), CTRL, RM, 0xf, false);
    return fminf(v, __int_as_float(t));
}
template<int CTRL, int RM>
__device__ __forceinline__ float dpp_max(float v) {
    int t = __builtin_amdgcn_update_dpp(0xff800000, __float_as_int(v), CTRL, RM, 0xf, false);
    return fmaxf(v, __int_as_float(t));
}

__device__ __forceinline__ float wave_sum(float v) {
    v = dpp_add<0x111, 0xf>(v);   // row_shr:1
    v = dpp_add<0x112, 0xf>(v);   // row_shr:2
    v = dpp_add<0x114, 0xf>(v);   // row_shr:4
    v = dpp_add<0x118, 0xf>(v);   // row_shr:8
    v = dpp_add<0x142, 0xa>(v);   // row_bcast:15
    v = dpp_add<0x143, 0xc>(v);   // row_bcast:31
    return __int_as_float(__builtin_amdgcn_readlane(__float_as_int(v), 63));
}
__device__ __forceinline__ float wave_min(float v) {
    v = dpp_min<0x111, 0xf>(v);
    v = dpp_min<0x112, 0xf>(v);
    v = dpp_min<0x114, 0xf>(v);
    v = dpp_min<0x118, 0xf>(v);
    v = dpp_min<0x142, 0xa>(v);
    v = dpp_min<0x143, 0xc>(v);
    return __int_as_float(__builtin_amdgcn_readlane(__float_as_int(v), 63));
}
__device__ __forceinline__ float wave_max(float v) {
    v = dpp_max<0x111, 0xf>(v);
    v = dpp_max<0x112, 0xf>(v);
    v = dpp_max<0x114, 0xf>(v);
    v = dpp_max<0x118, 0xf>(v);
    v = dpp_max<0x142, 0xa>(v);
    v = dpp_max<0x143, 0xc>(v);
    return __int_as_float(__builtin_amdgcn_readlane(__float_as_int(v), 63));
}

__global__ __launch_bounds__(256) void qp_proj_n4096(
    const float* __restrict__ z,
    const float* __restrict__ gamma,
    const float* __restrict__ mlo,
    const float* __restrict__ mhi,
    const float* __restrict__ xi,
    float* __restrict__ out)
{
    constexpr int N = 4096;
    const int row  = blockIdx.x;
    const int tid  = threadIdx.x;     // 0..255
    const int lane = tid & 63;
    const int wid  = tid >> 6;        // 0..3

    const float4* zrow = reinterpret_cast<const float4*>(z + (size_t)row * N);
    const float4* g4   = reinterpret_cast<const float4*>(gamma);
    const float4* m4   = reinterpret_cast<const float4*>(mlo);
    const float4* M4   = reinterpret_cast<const float4*>(mhi);
    float4*       orow = reinterpret_cast<float4*>(out + (size_t)row * N);

    // Per-thread element state (static indices after full unroll -> registers).
    float za[16], ia[16], ma[16], Ma[16];

    float pmin =  INFINITY;   // partial min of 2g*(m - z)
    float pmax = -INFINITY;   // partial max of 2g*(M - z)

    #pragma unroll
    for (int k = 0; k < 4; ++k) {
        const int idx = tid + k * 256;           // float4 index, coalesced
        const float4 zz = zrow[idx];
        const float4 gg = g4[idx];
        const float4 mm = m4[idx];
        const float4 MM = M4[idx];

        const float zs[4] = {zz.x, zz.y, zz.z, zz.w};
        const float gs[4] = {gg.x, gg.y, gg.z, gg.w};
        const float ms[4] = {mm.x, mm.y, mm.z, mm.w};
        const float Ms[4] = {MM.x, MM.y, MM.z, MM.w};

        #pragma unroll
        for (int c = 0; c < 4; ++c) {
            const int j = 4 * k + c;
            const float tg = 2.0f * gs[c];
            za[j] = zs[c];
            ia[j] = 1.0f / tg;
            ma[j] = ms[c];
            Ma[j] = Ms[c];
            pmin = fminf(pmin, tg * (ms[c] - zs[c]));
            pmax = fmaxf(pmax, tg * (Ms[c] - zs[c]));
        }
    }

    // ---- block reduce initial bounds ----
    __shared__ float wmin[4], wmax[4];
    __shared__ float wsum[2][3][4];   // [buf][probe][wave]; one barrier/iter

    pmin = wave_min(pmin);
    pmax = wave_max(pmax);
    if (lane == 0) { wmin[wid] = pmin; wmax[wid] = pmax; }
    __syncthreads();
    float lo = fminf(fminf(wmin[0], wmin[1]), fminf(wmin[2], wmin[3]));
    float hi = fmaxf(fmaxf(wmax[0], wmax[1]), fmaxf(wmax[2], wmax[3]));

    const float xir = xi[row];

    // ---- quadrisection: 3 probes/iter, interval shrinks 4x ----
    #pragma unroll
    for (int it = 0; it < QITERS; ++it) {
        const float w4 = 0.25f * (hi - lo);
        const float l1 = lo + w4;
        const float l2 = fmaf(2.0f, w4, lo);
        const float l3 = fmaf(3.0f, w4, lo);

        float s1 = 0.0f, s2 = 0.0f, s3 = 0.0f;
        #pragma unroll
        for (int j = 0; j < 16; ++j) {
            const float b = za[j], d = ia[j], a = ma[j], A = Ma[j];
            s1 += __builtin_amdgcn_fmed3f(fmaf(l1, d, b), a, A);
            s2 += __builtin_amdgcn_fmed3f(fmaf(l2, d, b), a, A);
            s3 += __builtin_amdgcn_fmed3f(fmaf(l3, d, b), a, A);
        }
        // three independent DPP chains interleave
        s1 = wave_sum(s1);
        s2 = wave_sum(s2);
        s3 = wave_sum(s3);

        const int p = it & 1;
        if (lane == 0) {
            wsum[p][0][wid] = s1;
            wsum[p][1][wid] = s2;
            wsum[p][2][wid] = s3;
        }
        __syncthreads();
        // iter it's write to buf p is protected from iter it-2's reads of
        // buf p by the barrier in iter it-1 -> single barrier suffices.
        const float g1 = (wsum[p][0][0] + wsum[p][0][1] + wsum[p][0][2] + wsum[p][0][3]) - xir;
        const float g2 = (wsum[p][1][0] + wsum[p][1][1] + wsum[p][1][2] + wsum[p][1][3]) - xir;
        const float g3 = (wsum[p][2][0] + wsum[p][2][1] + wsum[p][2][2] + wsum[p][2][3]) - xir;

        // reference semantics: g > 0 -> root below; g <= 0 -> root above.
        const int c = (g1 <= 0.0f) + (g2 <= 0.0f) + (g3 <= 0.0f);
        const float fc = (float)c;
        const float nlo = fmaf(fc, w4, lo);
        const float nhi = (c == 3) ? hi : fmaf(fc + 1.0f, w4, lo);
        lo = nlo;
        hi = nhi;
    }

    const float lam = 0.5f * (lo + hi);

    // ---- final x ----
    #pragma unroll
    for (int k = 0; k < 4; ++k) {
        const int idx = tid + k * 256;
        float4 r;
        float xs[4];
        #pragma unroll
        for (int c2 = 0; c2 < 4; ++c2) {
            const int j = 4 * k + c2;
            const float x = fmaf(lam, ia[j], za[j]);
            xs[c2] = __builtin_amdgcn_fmed3f(x, ma[j], Ma[j]);
        }
        r.x = xs[0]; r.y = xs[1]; r.z = xs[2]; r.w = xs[3];
        orow[idx] = r;
    }
}

extern "C" void kernel_launch(void* const* d_in, const int* in_sizes, int n_in,
                              void* d_out, int out_size, void* d_ws, size_t ws_size,
                              hipStream_t stream) {
    const float* z     = (const float*)d_in[0];
    const float* gamma = (const float*)d_in[1];
    const float* m     = (const float*)d_in[2];
    const float* M     = (const float*)d_in[3];
    const float* xi    = (const float*)d_in[4];
    float* out = (float*)d_out;

    const int B = in_sizes[4];   // rows (xi has one entry per row)
    // Kernel is specialized to N == 4096 (16 elements / thread, 256 threads).
    qp_proj_n4096<<<dim3(B), dim3(256), 0, stream>>>(z, gamma, m, M, xi, out);
}